// Round 10
// baseline (2535.444 us; speedup 1.0000x reference)
//
#include <hip/hip_runtime.h>
#include <hip/hip_bf16.h>

typedef __attribute__((ext_vector_type(8))) __bf16 bf16x8;
typedef __attribute__((ext_vector_type(16))) float f32x16;
typedef __attribute__((ext_vector_type(4)))  float f32x4;

#define NB 256     // batch
#define HD 1024    // hidden
#define G3 3072    // 3*H
#define NT 128     // time steps

// ---------------- workspace layout (bytes) ----------------
static const size_t OFF_WHH  = 0;                                   // [d][3072][1024] bf16 (natural)
static const size_t OFF_WIH  = OFF_WHH + (size_t)2*G3*HD*2;         // [d][3072][1024] bf16 (natural)
static const size_t OFF_X16  = OFF_WIH + (size_t)2*G3*HD*2;         // [256][1024] bf16 (natural)
static const size_t OFF_CTR  = OFF_X16 + (size_t)NB*HD*2;           // 8 group counters, 128B apart (1KB)
static const size_t OFF_H16  = OFF_CTR + 1024;                      // [p][d][256][1024] bf16 (natural)
static const size_t OFF_PART = OFF_H16 + (size_t)4*NB*HD*2;         // [b][t][64] f32
// total ~36.2 MB

// ---------------- prep: cast to bf16, zero h16 parity 0, zero barrier ctrs ----------------
__global__ __launch_bounds__(256) void prep_kernel(
    const float* __restrict__ x,    const float* __restrict__ wihf,
    const float* __restrict__ whhf, const float* __restrict__ wihb,
    const float* __restrict__ whhb, char* __restrict__ ws)
{
  size_t i = (size_t)blockIdx.x*256 + threadIdx.x;   // grid covers 3145728
  __hip_bfloat16* whh = (__hip_bfloat16*)(ws+OFF_WHH);
  __hip_bfloat16* wih = (__hip_bfloat16*)(ws+OFF_WIH);
  __hip_bfloat16* x16 = (__hip_bfloat16*)(ws+OFF_X16);
  __hip_bfloat16* h16 = (__hip_bfloat16*)(ws+OFF_H16);
  if (blockIdx.x==0 && threadIdx.x<256) ((unsigned*)(ws+OFF_CTR))[threadIdx.x] = 0u;
  if (i < (size_t)G3*HD) {
    whh[i]                 = __float2bfloat16(whhf[i]);
    whh[(size_t)G3*HD + i] = __float2bfloat16(whhb[i]);
    wih[i]                 = __float2bfloat16(wihf[i]);
    wih[(size_t)G3*HD + i] = __float2bfloat16(wihb[i]);
  }
  if (i < (size_t)NB*HD)   x16[i] = __float2bfloat16(x[i]);
  if (i < (size_t)2*NB*HD) h16[i]  = __float2bfloat16(0.f);   // parity-0 plane, both dirs
}

// ---------------- coherent-bypass (sc0 sc1) helpers ----------------
__device__ inline f32x4 gload_cc(const void* p){
  f32x4 r;
  asm volatile("global_load_dwordx4 %0, %1, off sc0 sc1" : "=v"(r) : "v"(p) : "memory");
  return r;
}
__device__ inline void gstore_cc_d1(void* p, unsigned v){
  asm volatile("global_store_dword %0, %1, off sc0 sc1" :: "v"(p), "v"(v) : "memory");
}

// ---------------- persistent bidirectional GRU ----------------
// 256 blocks (1/CU, pinned by 104KB LDS), 512 threads = 8 waves = 8 K-slices of 128.
// 2 waves/SIMD (launch_bounds 512,2 -> <=256 VGPR) for latency hiding.
// Rows: two sequential 32-row halves (rh) reusing one acc.
// bid&7 = (d<<2)|rt sync group as round 9 (32 jt-blocks per group, RMW barrier).
// W_hh frags resident in VGPR: B[3][8] = 96 VGPR for all 128 steps.
__global__ __launch_bounds__(512,2)
void gru_persist(char* __restrict__ ws,
                 const float* __restrict__ bihf, const float* __restrict__ bhhf,
                 const float* __restrict__ bihb, const float* __restrict__ bhhb,
                 const float* __restrict__ wout)
{
  const int bid = blockIdx.x;
  const int g8  = bid & 7;
  const int d   = g8 >> 2;
  const int rt  = g8 & 3;
  const int jt  = bid >> 3;
  const int tid = threadIdx.x;
  const int q   = tid >> 6;          // K-slice 0..7 (128 each)
  const int l   = tid & 63;
  const int lrow = l & 31;
  const int lh   = l >> 5;
  const int row_e = q*4 + (l>>4);    // epilogue row 0..31 within half
  const int ce    = (l & 15)*2;      // epilogue col pair 0..30
  const int r0 = rt*64, j0 = jt*32;

  const __hip_bfloat16* Wih = (const __hip_bfloat16*)(ws+OFF_WIH) + (size_t)d*G3*HD;
  const __hip_bfloat16* Whh = (const __hip_bfloat16*)(ws+OFF_WHH) + (size_t)d*G3*HD;
  const __hip_bfloat16* X16 = (const __hip_bfloat16*)(ws+OFF_X16);
  __hip_bfloat16* H16 = (__hip_bfloat16*)(ws+OFF_H16);
  unsigned* ctr = (unsigned*)(ws+OFF_CTR);
  float* part = (float*)(ws+OFF_PART);

  __shared__ float red[8][32][102];   // 104448 B; pad 102: conflict-free writes, <=4-way b64 reads

  const int kq = q*128 + lh*8;        // lane's base element offset in K

  bf16x8 B[3][8];                     // resident weight fragments (96 VGPR)
  #define LOADB(WSRC) { _Pragma("unroll") for (int g=0; g<3; ++g){ \
      const __hip_bfloat16* p0 = (WSRC) + (size_t)(g*1024 + j0 + lrow)*HD + kq; \
      _Pragma("unroll") for (int ks=0; ks<8; ++ks) B[g][ks] = *(const bf16x8*)(p0 + ks*16); } }

  f32x16 acc[3];
  #define ZACC { _Pragma("unroll") for (int g=0;g<3;++g) _Pragma("unroll") for (int e=0;e<16;++e) acc[g][e]=0.f; }
  #define MFMA8(AR) { _Pragma("unroll") for (int ks=0; ks<8; ++ks){ \
      bf16x8 a_ = __builtin_bit_cast(bf16x8, AR[ks]); \
      acc[0] = __builtin_amdgcn_mfma_f32_32x32x16_bf16(a_, B[0][ks], acc[0],0,0,0); \
      acc[1] = __builtin_amdgcn_mfma_f32_32x32x16_bf16(a_, B[1][ks], acc[1],0,0,0); \
      acc[2] = __builtin_amdgcn_mfma_f32_32x32x16_bf16(a_, B[2][ks], acc[2],0,0,0); } }
  #define WRED { _Pragma("unroll") for (int g=0;g<3;++g) _Pragma("unroll") for (int e=0;e<16;++e){ \
      int rl = (e&3) + 8*(e>>2) + 4*lh; red[q][rl][g*32 + lrow] = acc[g][e]; } }
  #define RRED(V) { _Pragma("unroll") for (int g=0;g<3;++g){ V[g][0]=0.f; V[g][1]=0.f; \
      _Pragma("unroll") for (int qq=0; qq<8; ++qq){ \
        float2 rd_ = *(const float2*)&red[qq][row_e][g*32 + ce]; V[g][0]+=rd_.x; V[g][1]+=rd_.y; } } }
  #define WAIT0 { asm volatile("s_waitcnt vmcnt(0)" ::: "memory"); __builtin_amdgcn_sched_barrier(0); }

  f32x4 A0[8], A1[8];
  #define ISSUE(AR, PA) { _Pragma("unroll") for (int ks=0; ks<8; ++ks) AR[ks] = gload_cc((PA) + ks*16); }

  // ---- INIT: gi = x @ W_ih^T, both row halves, captured to registers ----
  float gir[2][2], giz[2][2], gin[2][2], hst[2][2], v0[3][2], v1[3][2];
  LOADB(Wih);
  {
    const __hip_bfloat16* pa0 = X16 + (size_t)(r0 + lrow)*HD + kq;
    const __hip_bfloat16* pa1 = pa0 + 32*HD;
    ISSUE(A0, pa0);
    WAIT0;
    ZACC; MFMA8(A0);
    ISSUE(A1, pa1);
    WRED;
    __syncthreads();
    RRED(v0);
    __syncthreads();
    WAIT0;
    ZACC; MFMA8(A1);
    WRED;
    __syncthreads();
    RRED(v1);
    __syncthreads();
  }
  const float* bih = d ? bihb : bihf;
  const float* bhh = d ? bhhb : bhhf;
  float bhn[2], wo2[2];
  #pragma unroll
  for (int c=0;c<2;++c){
    const int col = j0 + ce + c;
    gir[0][c] = v0[0][c] + bih[col]      + bhh[col];
    giz[0][c] = v0[1][c] + bih[1024+col] + bhh[1024+col];
    gin[0][c] = v0[2][c] + bih[2048+col];
    gir[1][c] = v1[0][c] + bih[col]      + bhh[col];
    giz[1][c] = v1[1][c] + bih[1024+col] + bhh[1024+col];
    gin[1][c] = v1[2][c] + bih[2048+col];
    bhn[c] = bhh[2048+col];
    wo2[c] = wout[d*HD + col];
    hst[0][c] = 0.f; hst[1][c] = 0.f;
  }

  LOADB(Whh);                          // recurrent weights resident from here on
  const size_t hplane = (size_t)2*NB*HD;

  #define EPILOGUE(RH, V, T, HD_PTR) { \
    float pp_ = 0.f; \
    _Pragma("unroll") for (int c=0;c<2;++c){ \
      float rr_ = 1.f/(1.f+__expf(-(gir[RH][c]+V[0][c]))); \
      float zz_ = 1.f/(1.f+__expf(-(giz[RH][c]+V[1][c]))); \
      float ng_ = tanhf(gin[RH][c] + rr_*(V[2][c]+bhn[c])); \
      hst[RH][c] = (1.f-zz_)*ng_ + zz_*hst[RH][c]; \
      pp_ += hst[RH][c]*wo2[c]; \
    } \
    const int grow_ = r0 + (RH)*32 + row_e; \
    unsigned u_ = (unsigned)__builtin_bit_cast(unsigned short, (__bf16)hst[RH][0]) \
                | ((unsigned)__builtin_bit_cast(unsigned short, (__bf16)hst[RH][1]) << 16); \
    gstore_cc_d1((HD_PTR) + (size_t)grow_*HD + j0 + ce, u_); \
    pp_ += __shfl_xor(pp_, 1, 64); pp_ += __shfl_xor(pp_, 2, 64); \
    pp_ += __shfl_xor(pp_, 4, 64); pp_ += __shfl_xor(pp_, 8, 64); \
    if ((l & 15) == 0) part[((size_t)grow_*NT + (T))*64 + d*32 + jt] = pp_; \
  }

  for (int t=0; t<NT; ++t){
    const __hip_bfloat16* hs = H16 + (size_t)(t&1)*hplane + (size_t)d*NB*HD;
    __hip_bfloat16*       hd = H16 + (size_t)((t+1)&1)*hplane + (size_t)d*NB*HD;
    const __hip_bfloat16* pa0 = hs + (size_t)(r0 + lrow)*HD + kq;
    const __hip_bfloat16* pa1 = pa0 + 32*HD;

    ISSUE(A0, pa0);
    WAIT0;
    ZACC; MFMA8(A0);
    ISSUE(A1, pa1);                 // lands during the rh0 reduce
    WRED;
    __syncthreads();
    RRED(v0);
    __syncthreads();                // red free for rh1
    WAIT0;                          // A1 ready (no stores outstanding here)
    ZACC; MFMA8(A1);
    EPILOGUE(0, v0, t, hd);         // rh0 gates+stores, overlaps rh1 red-write
    WRED;
    __syncthreads();
    RRED(v1);
    EPILOGUE(1, v1, t, hd);

    if (t < NT-1){
      asm volatile("s_waitcnt vmcnt(0)" ::: "memory");  // drain own h stores (per-wave)
      __syncthreads();
      if (tid == 0){
        atomicAdd(&ctr[g8*32], 1u);
        const unsigned tgt = 32u*(unsigned)(t+1);
        while (__hip_atomic_load(&ctr[g8*32], __ATOMIC_RELAXED, __HIP_MEMORY_SCOPE_AGENT) < tgt)
          __builtin_amdgcn_s_sleep(1);
      }
      __syncthreads();
    }
  }
}

// ---------------- finalize: one wave per (b,t) output, f32 OUTPUT ----------------
__global__ __launch_bounds__(256) void finalize_kernel(
    const char* __restrict__ ws, const float* __restrict__ bout,
    float* __restrict__ out)
{
  int widx = blockIdx.x*4 + (threadIdx.x>>6);   // output index b*128+t, 32768 total
  int lane = threadIdx.x & 63;
  const float* part = (const float*)(ws+OFF_PART);
  float v = part[(size_t)widx*64 + lane];
  #pragma unroll
  for (int m=1;m<64;m<<=1) v += __shfl_xor(v, m, 64);
  if (lane==0) out[widx] = v + bout[0];
}

// ---------------- launch ----------------
extern "C" void kernel_launch(void* const* d_in, const int* in_sizes, int n_in,
                              void* d_out, int out_size, void* d_ws, size_t ws_size,
                              hipStream_t stream)
{
  const float* x    = (const float*)d_in[0];
  // d_in[1] = n (always 128 for this problem)
  const float* wihf = (const float*)d_in[2];
  const float* whhf = (const float*)d_in[3];
  const float* bihf = (const float*)d_in[4];
  const float* bhhf = (const float*)d_in[5];
  const float* wihb = (const float*)d_in[6];
  const float* whhb = (const float*)d_in[7];
  const float* bihb = (const float*)d_in[8];
  const float* bhhb = (const float*)d_in[9];
  const float* wout = (const float*)d_in[10];
  const float* bout = (const float*)d_in[11];
  char* ws = (char*)d_ws;
  float* out = (float*)d_out;

  prep_kernel<<<12288, 256, 0, stream>>>(x, wihf, whhf, wihb, whhb, ws);
  gru_persist<<<256, 512, 0, stream>>>(ws, bihf, bhhf, bihb, bhhb, wout);
  finalize_kernel<<<8192, 256, 0, stream>>>(ws, bout, out);
}